// Round 1
// baseline (663.679 us; speedup 1.0000x reference)
//
#include <hip/hip_runtime.h>
#include <hip/hip_bf16.h>
#include <math.h>

#define D 128
#define EPS 1e-5f

// ---------------- CSR build ----------------

__global__ void deg_kernel(const int* __restrict__ ei, int* __restrict__ cnt, int E) {
    int e = blockIdx.x * 256 + threadIdx.x;
    if (e >= E) return;
    atomicAdd(&cnt[ei[E + e]], 1);   // dst = ei[1][e]
}

__global__ void scan1_kernel(const int* __restrict__ cnt, int* __restrict__ rp1,
                             int* __restrict__ bsum, int Nn) {
    __shared__ int sh[256];
    int i = blockIdx.x * 256 + threadIdx.x;
    int x = (i < Nn) ? cnt[i] : 0;
    sh[threadIdx.x] = x;
    __syncthreads();
    for (int off = 1; off < 256; off <<= 1) {
        int t = (threadIdx.x >= off) ? sh[threadIdx.x - off] : 0;
        __syncthreads();
        sh[threadIdx.x] += t;
        __syncthreads();
    }
    if (i < Nn) rp1[i] = sh[threadIdx.x];             // inclusive within block
    if (threadIdx.x == 255) bsum[blockIdx.x] = sh[255];
}

__global__ void scan2_kernel(int* __restrict__ bsum, int nb) {
    __shared__ int sh[256];
    int tid = threadIdx.x;
    int x = (tid < nb) ? bsum[tid] : 0;
    sh[tid] = x;
    __syncthreads();
    for (int off = 1; off < 256; off <<= 1) {
        int t = (tid >= off) ? sh[tid - off] : 0;
        __syncthreads();
        sh[tid] += t;
        __syncthreads();
    }
    if (tid < nb) bsum[tid] = sh[tid] - x;            // exclusive
}

__global__ void scan3_kernel(int* __restrict__ row_ptr, const int* __restrict__ bsum, int Nn) {
    int i = blockIdx.x * 256 + threadIdx.x;
    if (i < Nn) row_ptr[i + 1] += bsum[blockIdx.x];
    if (i == 0) row_ptr[0] = 0;
}

__global__ void fill_kernel(const int* __restrict__ ei, const int* __restrict__ row_ptr,
                            int* __restrict__ cur, int* __restrict__ colA, int E) {
    int e = blockIdx.x * 256 + threadIdx.x;
    if (e >= E) return;
    int s = ei[e];
    int d = ei[E + e];
    int pos = row_ptr[d] + atomicAdd(&cur[d], 1);
    colA[pos] = s;
}

// ---------------- generic fp32 GEMM: C = res + A@B + bias, optional relu ----------------
// A [M,K] row-major, B [K,N] row-major, C [M,N]. N % 64 == 0, K % 32 == 0.

#define BM 64
#define BN 64
#define BK 32

__global__ __launch_bounds__(256) void gemm_kernel(
    const float* __restrict__ A, const float* __restrict__ B,
    const float* __restrict__ bias, const float* __restrict__ res,
    float* __restrict__ C, int M, int N, int K, int relu)
{
    __shared__ float As[BK][BM + 4];   // transposed A tile, padded (272B rows: 16B aligned)
    __shared__ float Bs[BK][BN];

    int tid = threadIdx.x;
    int tx = tid & 15;        // col group
    int ty = tid >> 4;        // row group
    int bm = blockIdx.x * BM;
    int bn = blockIdx.y * BN;

    float acc[4][4] = {};

    for (int kc = 0; kc < K; kc += BK) {
        // A tile: 64 rows x 32 k = 512 float4
        #pragma unroll
        for (int r = 0; r < 2; ++r) {
            int i = r * 256 + tid;
            int row = i >> 3;
            int kq = i & 7;
            int grow = bm + row;
            float4 a = make_float4(0.f, 0.f, 0.f, 0.f);
            if (grow < M)
                a = *(const float4*)&A[(size_t)grow * K + kc + kq * 4];
            As[kq * 4 + 0][row] = a.x;
            As[kq * 4 + 1][row] = a.y;
            As[kq * 4 + 2][row] = a.z;
            As[kq * 4 + 3][row] = a.w;
        }
        // B tile: 32 k x 64 n = 512 float4
        #pragma unroll
        for (int r = 0; r < 2; ++r) {
            int i = r * 256 + tid;
            int k = i >> 4;
            int n4 = i & 15;
            float4 b = *(const float4*)&B[(size_t)(kc + k) * N + bn + n4 * 4];
            *(float4*)&Bs[k][n4 * 4] = b;
        }
        __syncthreads();

        #pragma unroll
        for (int k = 0; k < BK; ++k) {
            float4 av = *(float4*)&As[k][ty * 4];
            float4 bv = *(float4*)&Bs[k][tx * 4];
            float a4[4] = {av.x, av.y, av.z, av.w};
            float b4[4] = {bv.x, bv.y, bv.z, bv.w};
            #pragma unroll
            for (int i = 0; i < 4; ++i)
                #pragma unroll
                for (int j = 0; j < 4; ++j)
                    acc[i][j] = fmaf(a4[i], b4[j], acc[i][j]);
        }
        __syncthreads();
    }

    float4 bias_v = *(const float4*)&bias[bn + tx * 4];
    float bv4[4] = {bias_v.x, bias_v.y, bias_v.z, bias_v.w};
    #pragma unroll
    for (int i = 0; i < 4; ++i) {
        int row = bm + ty * 4 + i;
        if (row >= M) continue;
        float4 out;
        float o[4];
        #pragma unroll
        for (int j = 0; j < 4; ++j) o[j] = acc[i][j] + bv4[j];
        if (res) {
            float4 rv = *(const float4*)&res[(size_t)row * N + bn + tx * 4];
            o[0] += rv.x; o[1] += rv.y; o[2] += rv.z; o[3] += rv.w;
        }
        if (relu) {
            #pragma unroll
            for (int j = 0; j < 4; ++j) o[j] = fmaxf(o[j], 0.f);
        }
        out.x = o[0]; out.y = o[1]; out.z = o[2]; out.w = o[3];
        *(float4*)&C[(size_t)row * N + bn + tx * 4] = out;
    }
}

// ---------------- attention: one wave per dst node, online softmax over CSR ----------------

__global__ __launch_bounds__(256) void attn_kernel(
    const float* __restrict__ q, const float* __restrict__ k, const float* __restrict__ v,
    const int* __restrict__ row_ptr, const int* __restrict__ colA,
    float* __restrict__ t, int Nn)
{
    int wave = threadIdx.x >> 6;
    int lane = threadIdx.x & 63;
    int n = blockIdx.x * 4 + wave;
    if (n >= Nn) return;

    int beg = row_ptr[n], end = row_ptr[n + 1];
    float q0 = q[(size_t)n * D + lane];
    float q1 = q[(size_t)n * D + 64 + lane];

    const float scale = 0.08838834764831845f;   // 1/sqrt(128)
    float m = -INFINITY, l = 0.f, a0 = 0.f, a1 = 0.f;

    for (int i = beg; i < end; ++i) {
        int s = colA[i];
        float d = q0 * k[(size_t)s * D + lane] + q1 * k[(size_t)s * D + 64 + lane];
        #pragma unroll
        for (int off = 32; off > 0; off >>= 1) d += __shfl_xor(d, off);
        float sc = d * scale;
        float nm = fmaxf(m, sc);
        float cold = __expf(m - nm);     // 0 on first edge (m = -inf)
        float p = __expf(sc - nm);
        l = l * cold + p;
        a0 = a0 * cold + p * v[(size_t)s * D + lane];
        a1 = a1 * cold + p * v[(size_t)s * D + 64 + lane];
        m = nm;
    }

    if (l > 0.f) {
        float inv = 1.f / l;
        t[(size_t)n * D + lane]      += a0 * inv;
        t[(size_t)n * D + 64 + lane] += a1 * inv;
    }
}

// ---------------- batch norm ----------------

__global__ __launch_bounds__(256) void bn_stats_kernel(const float* __restrict__ h,
                                                       float* __restrict__ stats, int Nn) {
    int c = threadIdx.x & 127;
    int half = threadIdx.x >> 7;
    float s = 0.f, s2 = 0.f;
    for (int r = blockIdx.x * 2 + half; r < Nn; r += gridDim.x * 2) {
        float x = h[(size_t)r * D + c];
        s += x;
        s2 += x * x;
    }
    __shared__ float sh[256], sh2[256];
    sh[threadIdx.x] = s;
    sh2[threadIdx.x] = s2;
    __syncthreads();
    if (threadIdx.x < 128) {
        atomicAdd(&stats[c], sh[threadIdx.x] + sh[threadIdx.x + 128]);
        atomicAdd(&stats[128 + c], sh2[threadIdx.x] + sh2[threadIdx.x + 128]);
    }
}

__global__ __launch_bounds__(256) void bn_apply_kernel(
    const float* __restrict__ h, const float* __restrict__ stats,
    const float* __restrict__ g, const float* __restrict__ b,
    float* __restrict__ out, int Nn)
{
    float invN = 1.f / (float)Nn;
    int total4 = Nn * (D / 4);
    for (int i4 = blockIdx.x * 256 + threadIdx.x; i4 < total4; i4 += gridDim.x * 256) {
        int cb = (i4 & 31) * 4;
        float4 x = ((const float4*)h)[i4];
        float xs[4] = {x.x, x.y, x.z, x.w};
        float o[4];
        #pragma unroll
        for (int j = 0; j < 4; ++j) {
            int c = cb + j;
            float mean = stats[c] * invN;
            float var = stats[128 + c] * invN - mean * mean;
            float inv = rsqrtf(var + EPS);
            o[j] = g[c] * (xs[j] - mean) * inv + b[c];
        }
        float4 ov = make_float4(o[0], o[1], o[2], o[3]);
        ((float4*)out)[i4] = ov;
    }
}

// ---------------- launch ----------------

extern "C" void kernel_launch(void* const* d_in, const int* in_sizes, int n_in,
                              void* d_out, int out_size, void* d_ws, size_t ws_size,
                              hipStream_t stream) {
    const float* x  = (const float*)d_in[0];
    const int*   ei = (const int*)d_in[1];
    const float* Wq = (const float*)d_in[2];  const float* bq = (const float*)d_in[3];
    const float* Wk = (const float*)d_in[4];  const float* bk = (const float*)d_in[5];
    const float* Wv = (const float*)d_in[6];  const float* bv = (const float*)d_in[7];
    const float* Ws = (const float*)d_in[8];  const float* bs = (const float*)d_in[9];
    const float* WO = (const float*)d_in[10]; const float* bO = (const float*)d_in[11];
    const float* W1 = (const float*)d_in[12]; const float* b1 = (const float*)d_in[13];
    const float* W2 = (const float*)d_in[14]; const float* b2 = (const float*)d_in[15];
    const float* g1 = (const float*)d_in[16]; const float* be1 = (const float*)d_in[17];
    const float* g2 = (const float*)d_in[18]; const float* be2 = (const float*)d_in[19];

    const int N = in_sizes[0] / D;        // 50000
    const int E = in_sizes[1] / 2;        // 800000
    float* out = (float*)d_out;

    // workspace layout
    size_t ND = (size_t)N * D;
    float* qb = (float*)d_ws;
    float* kb = qb + ND;
    float* vb = kb + ND;
    float* tb = vb + ND;                  // x@Ws+bs, then += attention agg
    float* hb = tb + ND;                  // pre-BN1 -> BN1 output (in place)
    float* zb = qb;                       // [N, 256] FFN hidden; aliases q,k (dead after attn)
    float* h2b = vb;                      // pre-BN2; aliases v (dead after attn)
    float* stats = hb + ND;               // 256 floats
    int* row_ptr = (int*)(stats + 256);   // N+1
    int* cnt = row_ptr + (N + 1);         // N
    int* colA = cnt + N;                  // E
    int* bsum = colA + E;                 // <=256

    int nb = (N + 255) / 256;             // scan blocks (196)
    int eb = (E + 255) / 256;

    // --- CSR build ---
    hipMemsetAsync(cnt, 0, (size_t)N * sizeof(int), stream);
    deg_kernel<<<eb, 256, 0, stream>>>(ei, cnt, E);
    scan1_kernel<<<nb, 256, 0, stream>>>(cnt, row_ptr + 1, bsum, N);
    scan2_kernel<<<1, 256, 0, stream>>>(bsum, nb);
    scan3_kernel<<<nb, 256, 0, stream>>>(row_ptr, bsum, N);
    hipMemsetAsync(cnt, 0, (size_t)N * sizeof(int), stream);
    fill_kernel<<<eb, 256, 0, stream>>>(ei, row_ptr, cnt, colA, E);

    // --- projections: q, k, v, skip(tb) ---
    dim3 g128((N + BM - 1) / BM, D / BN);
    gemm_kernel<<<g128, 256, 0, stream>>>(x, Wq, bq, nullptr, qb, N, D, D, 0);
    gemm_kernel<<<g128, 256, 0, stream>>>(x, Wk, bk, nullptr, kb, N, D, D, 0);
    gemm_kernel<<<g128, 256, 0, stream>>>(x, Wv, bv, nullptr, vb, N, D, D, 0);
    gemm_kernel<<<g128, 256, 0, stream>>>(x, Ws, bs, nullptr, tb, N, D, D, 0);

    // --- attention (one wave per dst node) ---
    attn_kernel<<<(N + 3) / 4, 256, 0, stream>>>(qb, kb, vb, row_ptr, colA, tb, N);

    // --- O projection + residual1: hb = x + tb@WO + bO ---
    gemm_kernel<<<g128, 256, 0, stream>>>(tb, WO, bO, x, hb, N, D, D, 0);

    // --- BN1 (in place on hb) ---
    hipMemsetAsync(stats, 0, 256 * sizeof(float), stream);
    bn_stats_kernel<<<256, 256, 0, stream>>>(hb, stats, N);
    bn_apply_kernel<<<1024, 256, 0, stream>>>(hb, stats, g1, be1, hb, N);

    // --- FFN ---
    dim3 g256((N + BM - 1) / BM, 2 * D / BN);
    gemm_kernel<<<g256, 256, 0, stream>>>(hb, W1, b1, nullptr, zb, N, 2 * D, D, 1);
    gemm_kernel<<<g128, 256, 0, stream>>>(zb, W2, b2, hb, h2b, N, D, 2 * D, 0);

    // --- BN2 -> out ---
    hipMemsetAsync(stats, 0, 256 * sizeof(float), stream);
    bn_stats_kernel<<<256, 256, 0, stream>>>(h2b, stats, N);
    bn_apply_kernel<<<1024, 256, 0, stream>>>(h2b, stats, g2, be2, out, N);
}

// Round 2
// 563.529 us; speedup vs baseline: 1.1777x; 1.1777x over previous
//
#include <hip/hip_runtime.h>
#include <hip/hip_bf16.h>
#include <math.h>

#define D 128
#define EPS 1e-5f

typedef unsigned short u16;
typedef short bf16x8 __attribute__((ext_vector_type(8)));
typedef float f32x4 __attribute__((ext_vector_type(4)));

static __device__ __forceinline__ u16 f2b(float f) {
    union { float f; unsigned u; } x{f};
    unsigned u = x.u;
    return (u16)((u + 0x7FFFu + ((u >> 16) & 1u)) >> 16);   // RNE
}
static __device__ __forceinline__ float bf2f(unsigned ubits) {
    union { unsigned u; float f; } x{ubits << 16};
    return x.f;
}

// ---------------- CSR build ----------------

__global__ void deg_kernel(const int* __restrict__ ei, int* __restrict__ cnt, int E) {
    int e = blockIdx.x * 256 + threadIdx.x;
    if (e >= E) return;
    atomicAdd(&cnt[ei[E + e]], 1);   // dst = ei[1][e]
}

__global__ void scan1_kernel(const int* __restrict__ cnt, int* __restrict__ rp1,
                             int* __restrict__ bsum, int Nn) {
    __shared__ int sh[256];
    int i = blockIdx.x * 256 + threadIdx.x;
    int x = (i < Nn) ? cnt[i] : 0;
    sh[threadIdx.x] = x;
    __syncthreads();
    for (int off = 1; off < 256; off <<= 1) {
        int t = (threadIdx.x >= off) ? sh[threadIdx.x - off] : 0;
        __syncthreads();
        sh[threadIdx.x] += t;
        __syncthreads();
    }
    if (i < Nn) rp1[i] = sh[threadIdx.x];
    if (threadIdx.x == 255) bsum[blockIdx.x] = sh[255];
}

__global__ void scan2_kernel(int* __restrict__ bsum, int nb) {
    __shared__ int sh[256];
    int tid = threadIdx.x;
    int x = (tid < nb) ? bsum[tid] : 0;
    sh[tid] = x;
    __syncthreads();
    for (int off = 1; off < 256; off <<= 1) {
        int t = (tid >= off) ? sh[tid - off] : 0;
        __syncthreads();
        sh[tid] += t;
        __syncthreads();
    }
    if (tid < nb) bsum[tid] = sh[tid] - x;   // exclusive
}

__global__ void scan3_kernel(int* __restrict__ row_ptr, const int* __restrict__ bsum, int Nn) {
    int i = blockIdx.x * 256 + threadIdx.x;
    if (i < Nn) row_ptr[i + 1] += bsum[blockIdx.x];
    if (i == 0) row_ptr[0] = 0;
}

__global__ void fill_kernel(const int* __restrict__ ei, const int* __restrict__ row_ptr,
                            int* __restrict__ cur, int* __restrict__ colA, int E) {
    int e = blockIdx.x * 256 + threadIdx.x;
    if (e >= E) return;
    int s = ei[e];
    int d = ei[E + e];
    int pos = row_ptr[d] + atomicAdd(&cur[d], 1);
    colA[pos] = s;
}

// ---------------- fp32 -> bf16 convert ----------------

__global__ __launch_bounds__(256) void cvt_kernel(const float* __restrict__ in,
                                                  u16* __restrict__ out, int n4) {
    int stride = gridDim.x * 256;
    for (int i = blockIdx.x * 256 + threadIdx.x; i < n4; i += stride) {
        float4 x = ((const float4*)in)[i];
        unsigned lo = (unsigned)f2b(x.x) | ((unsigned)f2b(x.y) << 16);
        unsigned hi = (unsigned)f2b(x.z) | ((unsigned)f2b(x.w) << 16);
        ((uint2*)out)[i] = make_uint2(lo, hi);
    }
}

// ---------------- weight prep: W[K][Nout] fp32 -> WT[Nout][K] bf16 ----------------
// K, Nout multiples of 32. block (32,8), grid (Nout/32, K/32)

__global__ void wprep_kernel(const float* __restrict__ W, u16* __restrict__ WT,
                             int K, int Nout) {
    __shared__ u16 t[32][33];
    int bx = blockIdx.x * 32;   // n tile
    int by = blockIdx.y * 32;   // k tile
    int tx = threadIdx.x, ty = threadIdx.y;
    #pragma unroll
    for (int r = 0; r < 32; r += 8)
        t[ty + r][tx] = f2b(W[(size_t)(by + ty + r) * Nout + bx + tx]);
    __syncthreads();
    #pragma unroll
    for (int r = 0; r < 32; r += 8)
        WT[(size_t)(bx + ty + r) * K + by + tx] = t[tx][ty + r];
}

// ---------------- bf16 MFMA GEMM ----------------
// A [M][K] bf16, BT [Nout][K] bf16, bias fp32.
// C fp32 (optional), C16 bf16 (optional), res fp32 (optional), relu flag.
// Tile: 128x128, BK=64. 4 waves in 2x2, each wave 4x4 tiles of 16x16x32.

#define GBM 128
#define GBK 64
#define LDA 72   // padded LDS row (64 + 8 bf16): 2-way-max bank aliasing (free)

__global__ __launch_bounds__(256) void gemm_bf16_kernel(
    const u16* __restrict__ A, const u16* __restrict__ BT,
    const float* __restrict__ bias, const float* __restrict__ res,
    float* __restrict__ C, u16* __restrict__ C16,
    int M, int K, int Nout, int relu)
{
    __shared__ u16 As[GBM * LDA];
    __shared__ u16 Bs[GBM * LDA];

    int tid = threadIdx.x;
    int wave = tid >> 6;
    int lane = tid & 63;
    int wm = (wave >> 1) * 64;
    int wn = (wave & 1) * 64;
    int bm = blockIdx.x * GBM;
    int bn = blockIdx.y * GBM;
    int lrow = lane & 15;
    int lquad = lane >> 4;

    f32x4 acc[4][4];
    #pragma unroll
    for (int i = 0; i < 4; ++i)
        #pragma unroll
        for (int j = 0; j < 4; ++j)
            acc[i][j] = (f32x4)0.f;

    for (int kc = 0; kc < K; kc += GBK) {
        #pragma unroll
        for (int r = 0; r < 4; ++r) {
            int c = r * 256 + tid;
            int row = c >> 3, grp = c & 7;
            int grow = bm + row;
            grow = grow < M ? grow : M - 1;           // clamp: garbage rows never stored
            uint4 d = *(const uint4*)&A[(size_t)grow * K + kc + grp * 8];
            *(uint4*)&As[row * LDA + grp * 8] = d;
        }
        #pragma unroll
        for (int r = 0; r < 4; ++r) {
            int c = r * 256 + tid;
            int row = c >> 3, grp = c & 7;
            uint4 d = *(const uint4*)&BT[(size_t)(bn + row) * K + kc + grp * 8];
            *(uint4*)&Bs[row * LDA + grp * 8] = d;
        }
        __syncthreads();
        #pragma unroll
        for (int ks = 0; ks < 2; ++ks) {
            bf16x8 af[4], bfr[4];
            #pragma unroll
            for (int i = 0; i < 4; ++i)
                af[i] = *(const bf16x8*)&As[(wm + i * 16 + lrow) * LDA + ks * 32 + lquad * 8];
            #pragma unroll
            for (int j = 0; j < 4; ++j)
                bfr[j] = *(const bf16x8*)&Bs[(wn + j * 16 + lrow) * LDA + ks * 32 + lquad * 8];
            #pragma unroll
            for (int i = 0; i < 4; ++i)
                #pragma unroll
                for (int j = 0; j < 4; ++j)
                    acc[i][j] = __builtin_amdgcn_mfma_f32_16x16x32_bf16(af[i], bfr[j], acc[i][j], 0, 0, 0);
        }
        __syncthreads();
    }

    // C/D layout: col = lane&15, row = (lane>>4)*4 + reg
    #pragma unroll
    for (int i = 0; i < 4; ++i) {
        #pragma unroll
        for (int r4 = 0; r4 < 4; ++r4) {
            int row = bm + wm + i * 16 + lquad * 4 + r4;
            if (row >= M) continue;
            #pragma unroll
            for (int j = 0; j < 4; ++j) {
                int col = bn + wn + j * 16 + lrow;
                float o = acc[i][j][r4] + bias[col];
                if (res) o += res[(size_t)row * Nout + col];
                if (relu) o = fmaxf(o, 0.f);
                if (C)   C[(size_t)row * Nout + col] = o;
                if (C16) C16[(size_t)row * Nout + col] = f2b(o);
            }
        }
    }
}

// ---------------- attention: one wave per dst node, online softmax, bf16 ----------------

__global__ __launch_bounds__(256) void attn_kernel(
    const u16* __restrict__ q, const u16* __restrict__ k, const u16* __restrict__ v,
    const int* __restrict__ row_ptr, const int* __restrict__ colA,
    u16* __restrict__ t, int Nn)
{
    int wave = threadIdx.x >> 6;
    int lane = threadIdx.x & 63;
    int n = blockIdx.x * 4 + wave;
    if (n >= Nn) return;

    int beg = row_ptr[n], end = row_ptr[n + 1];
    unsigned qu = *(const unsigned*)&q[(size_t)n * D + lane * 2];
    float q0 = bf2f(qu & 0xffffu), q1 = bf2f(qu >> 16);

    const float scale = 0.08838834764831845f;   // 1/sqrt(128)
    float m = -INFINITY, l = 0.f, a0 = 0.f, a1 = 0.f;

    int i = beg;
    for (; i + 2 <= end; i += 2) {
        int s0 = colA[i], s1 = colA[i + 1];
        unsigned k0 = *(const unsigned*)&k[(size_t)s0 * D + lane * 2];
        unsigned k1 = *(const unsigned*)&k[(size_t)s1 * D + lane * 2];
        unsigned v0 = *(const unsigned*)&v[(size_t)s0 * D + lane * 2];
        unsigned v1 = *(const unsigned*)&v[(size_t)s1 * D + lane * 2];
        float d0 = q0 * bf2f(k0 & 0xffffu) + q1 * bf2f(k0 >> 16);
        float d1 = q0 * bf2f(k1 & 0xffffu) + q1 * bf2f(k1 >> 16);
        #pragma unroll
        for (int off = 32; off; off >>= 1) {
            d0 += __shfl_xor(d0, off);
            d1 += __shfl_xor(d1, off);
        }
        float sc = d0 * scale;
        float nm = fmaxf(m, sc);
        float co = __expf(m - nm), p = __expf(sc - nm);
        l = l * co + p;
        a0 = a0 * co + p * bf2f(v0 & 0xffffu);
        a1 = a1 * co + p * bf2f(v0 >> 16);
        m = nm;
        sc = d1 * scale;
        nm = fmaxf(m, sc);
        co = __expf(m - nm); p = __expf(sc - nm);
        l = l * co + p;
        a0 = a0 * co + p * bf2f(v1 & 0xffffu);
        a1 = a1 * co + p * bf2f(v1 >> 16);
        m = nm;
    }
    for (; i < end; ++i) {
        int s = colA[i];
        unsigned ku = *(const unsigned*)&k[(size_t)s * D + lane * 2];
        unsigned vu = *(const unsigned*)&v[(size_t)s * D + lane * 2];
        float d = q0 * bf2f(ku & 0xffffu) + q1 * bf2f(ku >> 16);
        #pragma unroll
        for (int off = 32; off; off >>= 1) d += __shfl_xor(d, off);
        float sc = d * scale;
        float nm = fmaxf(m, sc);
        float co = __expf(m - nm), p = __expf(sc - nm);
        l = l * co + p;
        a0 = a0 * co + p * bf2f(vu & 0xffffu);
        a1 = a1 * co + p * bf2f(vu >> 16);
        m = nm;
    }

    if (l > 0.f) {
        float inv = 1.f / l;
        unsigned tu = *(const unsigned*)&t[(size_t)n * D + lane * 2];
        float t0 = bf2f(tu & 0xffffu) + a0 * inv;
        float t1 = bf2f(tu >> 16) + a1 * inv;
        *(unsigned*)&t[(size_t)n * D + lane * 2] =
            (unsigned)f2b(t0) | ((unsigned)f2b(t1) << 16);
    }
}

// ---------------- batch norm ----------------

__global__ __launch_bounds__(256) void bn_stats_kernel(const float* __restrict__ h,
                                                       float* __restrict__ stats, int Nn) {
    int c = threadIdx.x & 127;
    int half = threadIdx.x >> 7;
    float s = 0.f, s2 = 0.f;
    for (int r = blockIdx.x * 2 + half; r < Nn; r += gridDim.x * 2) {
        float x = h[(size_t)r * D + c];
        s += x;
        s2 += x * x;
    }
    __shared__ float sh[256], sh2[256];
    sh[threadIdx.x] = s;
    sh2[threadIdx.x] = s2;
    __syncthreads();
    if (threadIdx.x < 128) {
        atomicAdd(&stats[c], sh[threadIdx.x] + sh[threadIdx.x + 128]);
        atomicAdd(&stats[128 + c], sh2[threadIdx.x] + sh2[threadIdx.x + 128]);
    }
}

__global__ __launch_bounds__(256) void bn_apply_kernel(
    const float* __restrict__ h, const float* __restrict__ stats,
    const float* __restrict__ g, const float* __restrict__ b,
    float* __restrict__ out, u16* __restrict__ out16, int Nn)
{
    float invN = 1.f / (float)Nn;
    int total4 = Nn * (D / 4);
    for (int i4 = blockIdx.x * 256 + threadIdx.x; i4 < total4; i4 += gridDim.x * 256) {
        int cb = (i4 & 31) * 4;
        float4 x = ((const float4*)h)[i4];
        float xs[4] = {x.x, x.y, x.z, x.w};
        float o[4];
        #pragma unroll
        for (int j = 0; j < 4; ++j) {
            int c = cb + j;
            float mean = stats[c] * invN;
            float var = stats[128 + c] * invN - mean * mean;
            float inv = rsqrtf(var + EPS);
            o[j] = g[c] * (xs[j] - mean) * inv + b[c];
        }
        if (out)
            ((float4*)out)[i4] = make_float4(o[0], o[1], o[2], o[3]);
        if (out16) {
            unsigned lo = (unsigned)f2b(o[0]) | ((unsigned)f2b(o[1]) << 16);
            unsigned hi = (unsigned)f2b(o[2]) | ((unsigned)f2b(o[3]) << 16);
            ((uint2*)out16)[i4] = make_uint2(lo, hi);
        }
    }
}

// ---------------- launch ----------------

extern "C" void kernel_launch(void* const* d_in, const int* in_sizes, int n_in,
                              void* d_out, int out_size, void* d_ws, size_t ws_size,
                              hipStream_t stream) {
    const float* x  = (const float*)d_in[0];
    const int*   ei = (const int*)d_in[1];
    const float* Wq = (const float*)d_in[2];  const float* bq = (const float*)d_in[3];
    const float* Wk = (const float*)d_in[4];  const float* bk = (const float*)d_in[5];
    const float* Wv = (const float*)d_in[6];  const float* bv = (const float*)d_in[7];
    const float* Ws = (const float*)d_in[8];  const float* bs = (const float*)d_in[9];
    const float* WO = (const float*)d_in[10]; const float* bO = (const float*)d_in[11];
    const float* W1 = (const float*)d_in[12]; const float* b1 = (const float*)d_in[13];
    const float* W2 = (const float*)d_in[14]; const float* b2 = (const float*)d_in[15];
    const float* g1 = (const float*)d_in[16]; const float* be1 = (const float*)d_in[17];
    const float* g2 = (const float*)d_in[18]; const float* be2 = (const float*)d_in[19];

    const int N = in_sizes[0] / D;        // 50000
    const int E = in_sizes[1] / 2;        // 800000
    float* out = (float*)d_out;

    // ---- workspace layout (~94 MB) ----
    size_t ND = (size_t)N * D;
    u16* x16 = (u16*)d_ws;                // ND bf16
    u16* q16 = x16 + ND;
    u16* k16 = q16 + ND;
    u16* v16 = k16 + ND;
    u16* t16 = v16 + ND;
    float* hb = (float*)(t16 + ND);       // ND fp32 (pre/post BN1, long-lived)
    u16* hb16 = x16;                      // alias: x16 dead after projections
    u16* zb16 = q16;                      // [N][256] bf16, aliases q16+k16 (dead after attn)
    float* h2 = (float*)v16;              // [N][128] fp32, aliases v16+t16 (dead after O-proj)
    float* stats = hb + ND;               // 256 f
    u16* WqT = (u16*)(stats + 256);       // [128][128]
    u16* WkT = WqT + 128 * 128;
    u16* WvT = WkT + 128 * 128;
    u16* WsT = WvT + 128 * 128;
    u16* WOT = WsT + 128 * 128;
    u16* W1T = WOT + 128 * 128;           // [256][128]
    u16* W2T = W1T + 256 * 128;           // [128][256]
    int* row_ptr = (int*)(W2T + 256 * 128);  // N+1
    int* cnt = row_ptr + (N + 1);         // N
    int* colA = cnt + N;                  // E
    int* bsum = colA + E;                 // <=256

    int nb = (N + 255) / 256;
    int eb = (E + 255) / 256;

    // --- CSR build ---
    hipMemsetAsync(cnt, 0, (size_t)N * sizeof(int), stream);
    deg_kernel<<<eb, 256, 0, stream>>>(ei, cnt, E);
    scan1_kernel<<<nb, 256, 0, stream>>>(cnt, row_ptr + 1, bsum, N);
    scan2_kernel<<<1, 256, 0, stream>>>(bsum, nb);
    scan3_kernel<<<nb, 256, 0, stream>>>(row_ptr, bsum, N);
    hipMemsetAsync(cnt, 0, (size_t)N * sizeof(int), stream);
    fill_kernel<<<eb, 256, 0, stream>>>(ei, row_ptr, cnt, colA, E);

    // --- convert x, prep weights ---
    cvt_kernel<<<2048, 256, 0, stream>>>(x, x16, (int)(ND / 4));
    wprep_kernel<<<dim3(4, 4), dim3(32, 8), 0, stream>>>(Wq, WqT, 128, 128);
    wprep_kernel<<<dim3(4, 4), dim3(32, 8), 0, stream>>>(Wk, WkT, 128, 128);
    wprep_kernel<<<dim3(4, 4), dim3(32, 8), 0, stream>>>(Wv, WvT, 128, 128);
    wprep_kernel<<<dim3(4, 4), dim3(32, 8), 0, stream>>>(Ws, WsT, 128, 128);
    wprep_kernel<<<dim3(4, 4), dim3(32, 8), 0, stream>>>(WO, WOT, 128, 128);
    wprep_kernel<<<dim3(8, 4), dim3(32, 8), 0, stream>>>(W1, W1T, 128, 256);
    wprep_kernel<<<dim3(4, 8), dim3(32, 8), 0, stream>>>(W2, W2T, 256, 128);

    int gm = (N + GBM - 1) / GBM;   // 391

    // --- projections: q, k, v, skip(t16), all bf16 out ---
    gemm_bf16_kernel<<<dim3(gm, 1), 256, 0, stream>>>(x16, WqT, bq, nullptr, nullptr, q16, N, 128, 128, 0);
    gemm_bf16_kernel<<<dim3(gm, 1), 256, 0, stream>>>(x16, WkT, bk, nullptr, nullptr, k16, N, 128, 128, 0);
    gemm_bf16_kernel<<<dim3(gm, 1), 256, 0, stream>>>(x16, WvT, bv, nullptr, nullptr, v16, N, 128, 128, 0);
    gemm_bf16_kernel<<<dim3(gm, 1), 256, 0, stream>>>(x16, WsT, bs, nullptr, nullptr, t16, N, 128, 128, 0);

    // --- attention (adds into t16) ---
    attn_kernel<<<(N + 3) / 4, 256, 0, stream>>>(q16, k16, v16, row_ptr, colA, t16, N);

    // --- O projection + residual1: hb = x + t16@WO + bO (fp32 out) ---
    gemm_bf16_kernel<<<dim3(gm, 1), 256, 0, stream>>>(t16, WOT, bO, x, hb, nullptr, N, 128, 128, 0);

    // --- BN1: hb -> hb (fp32) + hb16 (bf16) ---
    hipMemsetAsync(stats, 0, 256 * sizeof(float), stream);
    bn_stats_kernel<<<256, 256, 0, stream>>>(hb, stats, N);
    bn_apply_kernel<<<1024, 256, 0, stream>>>(hb, stats, g1, be1, hb, hb16, N);

    // --- FFN: z = relu(h@W1+b1) bf16; h2 = hb + z@W2 + b2 fp32 ---
    gemm_bf16_kernel<<<dim3(gm, 2), 256, 0, stream>>>(hb16, W1T, b1, nullptr, nullptr, zb16, N, 128, 256, 1);
    gemm_bf16_kernel<<<dim3(gm, 1), 256, 0, stream>>>(zb16, W2T, b2, hb, h2, nullptr, N, 256, 128, 0);

    // --- BN2 -> out ---
    hipMemsetAsync(stats, 0, 256 * sizeof(float), stream);
    bn_stats_kernel<<<256, 256, 0, stream>>>(h2, stats, N);
    bn_apply_kernel<<<1024, 256, 0, stream>>>(h2, stats, g2, be2, out, nullptr, N);
}